// Round 1
// baseline (318.209 us; speedup 1.0000x reference)
//
#include <hip/hip_runtime.h>

#define NCH 256
#define NGRAPH 512
#define HID 16

// One block per graph. batch is sorted, so each graph's rows are a contiguous
// range found by binary search. Pool -> SE-MLP -> scale, fully fused.
__global__ __launch_bounds__(512, 2) void graph_se_kernel(
    const float* __restrict__ x,
    const int* __restrict__ batch,
    const float* __restrict__ W1,
    const float* __restrict__ W2,
    float* __restrict__ out,
    int n)
{
    const int g   = blockIdx.x;
    const int tid = threadIdx.x;

    __shared__ int   s_se[2];
    __shared__ float s_part[8][NCH];   // per-row-group partial sums
    __shared__ float s_vec[NCH];       // mean, then scale
    __shared__ float s_hp[HID][17];    // h partials (padded)
    __shared__ float s_h[HID];

    // --- row range via binary search (batch sorted) ---
    if (tid < 2) {
        int v = g + tid;
        int lo = 0, hi = n;
        while (lo < hi) { int mid = (lo + hi) >> 1; if (batch[mid] < v) lo = mid + 1; else hi = mid; }
        s_se[tid] = lo;
    }
    __syncthreads();
    const int start = s_se[0], end = s_se[1];
    const int cnt   = end - start;

    const int rg = tid >> 6;            // row group 0..7
    const int c4 = tid & 63;            // float4 lane within row
    const size_t coff = (size_t)c4 * 4;

    // --- pass 1: pooled sum (8 rows in parallel, 2x unrolled) ---
    float4 a0 = make_float4(0.f, 0.f, 0.f, 0.f);
    float4 a1 = make_float4(0.f, 0.f, 0.f, 0.f);
    int r = start + rg;
    for (; r + 8 < end; r += 16) {
        float4 v0 = *reinterpret_cast<const float4*>(x + (size_t)r * NCH + coff);
        float4 v1 = *reinterpret_cast<const float4*>(x + (size_t)(r + 8) * NCH + coff);
        a0.x += v0.x; a0.y += v0.y; a0.z += v0.z; a0.w += v0.w;
        a1.x += v1.x; a1.y += v1.y; a1.z += v1.z; a1.w += v1.w;
    }
    if (r < end) {
        float4 v0 = *reinterpret_cast<const float4*>(x + (size_t)r * NCH + coff);
        a0.x += v0.x; a0.y += v0.y; a0.z += v0.z; a0.w += v0.w;
    }
    a0.x += a1.x; a0.y += a1.y; a0.z += a1.z; a0.w += a1.w;
    *reinterpret_cast<float4*>(&s_part[rg][c4 * 4]) = a0;
    __syncthreads();

    // --- reduce 8 partials -> mean ---
    if (tid < NCH) {
        float m = 0.f;
        #pragma unroll
        for (int i = 0; i < 8; ++i) m += s_part[i][tid];
        m *= (cnt > 0) ? (1.0f / (float)cnt) : 1.0f;
        s_vec[tid] = m;
    }
    __syncthreads();

    // --- MLP: h = relu(mean @ W1), W1 [256,16] row-major ---
    if (tid < NCH) {
        const int j   = tid >> 4;   // 0..15 output unit
        const int sub = tid & 15;   // 0..15 partial over 16 channels
        float hp = 0.f;
        #pragma unroll
        for (int i = 0; i < 16; ++i) {
            int c = sub * 16 + i;
            hp += s_vec[c] * W1[c * HID + j];
        }
        s_hp[j][sub] = hp;
    }
    __syncthreads();
    if (tid < HID) {
        float h = 0.f;
        #pragma unroll
        for (int i = 0; i < 16; ++i) h += s_hp[tid][i];
        s_h[tid] = fmaxf(h, 0.f);
    }
    __syncthreads();

    // --- scale = sigmoid(h @ W2), W2 [16,256] row-major ---
    float sc = 0.f;
    if (tid < NCH) {
        #pragma unroll
        for (int j = 0; j < HID; ++j) sc += s_h[j] * W2[j * NCH + tid];
        sc = 1.0f / (1.0f + __expf(-sc));
    }
    __syncthreads();
    if (tid < NCH) s_vec[tid] = sc;
    __syncthreads();

    // --- pass 2: out = x * scale[g] over the same rows ---
    const float4 scv = *reinterpret_cast<const float4*>(&s_vec[c4 * 4]);
    r = start + rg;
    for (; r + 8 < end; r += 16) {
        float4 v0 = *reinterpret_cast<const float4*>(x + (size_t)r * NCH + coff);
        float4 v1 = *reinterpret_cast<const float4*>(x + (size_t)(r + 8) * NCH + coff);
        float4 o0, o1;
        o0.x = v0.x * scv.x; o0.y = v0.y * scv.y; o0.z = v0.z * scv.z; o0.w = v0.w * scv.w;
        o1.x = v1.x * scv.x; o1.y = v1.y * scv.y; o1.z = v1.z * scv.z; o1.w = v1.w * scv.w;
        *reinterpret_cast<float4*>(out + (size_t)r * NCH + coff) = o0;
        *reinterpret_cast<float4*>(out + (size_t)(r + 8) * NCH + coff) = o1;
    }
    if (r < end) {
        float4 v0 = *reinterpret_cast<const float4*>(x + (size_t)r * NCH + coff);
        float4 o0;
        o0.x = v0.x * scv.x; o0.y = v0.y * scv.y; o0.z = v0.z * scv.z; o0.w = v0.w * scv.w;
        *reinterpret_cast<float4*>(out + (size_t)r * NCH + coff) = o0;
    }
}

extern "C" void kernel_launch(void* const* d_in, const int* in_sizes, int n_in,
                              void* d_out, int out_size, void* d_ws, size_t ws_size,
                              hipStream_t stream) {
    const float* x     = (const float*)d_in[0];
    const int*   batch = (const int*)d_in[1];
    const float* W1    = (const float*)d_in[2];
    const float* W2    = (const float*)d_in[3];
    float*       out   = (float*)d_out;
    const int n = in_sizes[1];

    hipLaunchKernelGGL(graph_se_kernel, dim3(NGRAPH), dim3(512), 0, stream,
                       x, batch, W1, W2, out, n);
}

// Round 3
// 293.808 us; speedup vs baseline: 1.0831x; 1.0831x over previous
//
#include <hip/hip_runtime.h>

#define NCH 256
#define NGRAPH 512
#define HID 16

typedef __attribute__((ext_vector_type(4))) float f32x4;

// One block per graph (batch sorted -> contiguous row range via binary search).
// Pool -> SE-MLP -> scale, fully fused. 1024 threads = 16 row-groups of 64
// lanes (one float4-row per group) for 32 waves/CU occupancy.
__global__ __launch_bounds__(1024, 8) void graph_se_kernel(
    const float* __restrict__ x,
    const int* __restrict__ batch,
    const float* __restrict__ W1,
    const float* __restrict__ W2,
    float* __restrict__ out,
    int n)
{
    const int g   = blockIdx.x;
    const int tid = threadIdx.x;

    __shared__ int   s_se[2];
    __shared__ float s_part[16][NCH];  // per-row-group partial sums
    __shared__ float s_vec[NCH];       // mean, then scale
    __shared__ float s_hp[HID][17];    // h partials (padded)
    __shared__ float s_h[HID];

    // --- row range via binary search (batch sorted) ---
    if (tid < 2) {
        int v = g + tid;
        int lo = 0, hi = n;
        while (lo < hi) { int mid = (lo + hi) >> 1; if (batch[mid] < v) lo = mid + 1; else hi = mid; }
        s_se[tid] = lo;
    }
    __syncthreads();
    const int start = s_se[0], end = s_se[1];
    const int cnt   = end - start;

    const int rg = tid >> 6;            // row group 0..15
    const int c4 = tid & 63;            // float4 lane within row
    const size_t coff = (size_t)c4 * 4;

    // --- pass 1: pooled sum, 4 rows in flight per wave ---
    f32x4 acc = (f32x4)(0.f);
    int r = start + rg;
    for (; r + 48 < end; r += 64) {
        f32x4 v0 = *reinterpret_cast<const f32x4*>(x + (size_t)(r     ) * NCH + coff);
        f32x4 v1 = *reinterpret_cast<const f32x4*>(x + (size_t)(r + 16) * NCH + coff);
        f32x4 v2 = *reinterpret_cast<const f32x4*>(x + (size_t)(r + 32) * NCH + coff);
        f32x4 v3 = *reinterpret_cast<const f32x4*>(x + (size_t)(r + 48) * NCH + coff);
        acc += v0 + v1 + v2 + v3;
    }
    for (; r < end; r += 16) {
        acc += *reinterpret_cast<const f32x4*>(x + (size_t)r * NCH + coff);
    }
    *reinterpret_cast<f32x4*>(&s_part[rg][c4 * 4]) = acc;
    __syncthreads();

    // --- reduce 16 partials -> mean ---
    if (tid < NCH) {
        float m = 0.f;
        #pragma unroll
        for (int i = 0; i < 16; ++i) m += s_part[i][tid];
        m *= (cnt > 0) ? (1.0f / (float)cnt) : 1.0f;
        s_vec[tid] = m;
    }
    __syncthreads();

    // --- MLP: h = relu(mean @ W1), W1 [256,16] row-major ---
    if (tid < NCH) {
        const int j   = tid >> 4;   // 0..15 output unit
        const int sub = tid & 15;   // 0..15 partial over 16 channels
        float hp = 0.f;
        #pragma unroll
        for (int i = 0; i < 16; ++i) {
            int c = sub * 16 + i;
            hp += s_vec[c] * W1[c * HID + j];
        }
        s_hp[j][sub] = hp;
    }
    __syncthreads();
    if (tid < HID) {
        float h = 0.f;
        #pragma unroll
        for (int i = 0; i < 16; ++i) h += s_hp[tid][i];
        s_h[tid] = fmaxf(h, 0.f);
    }
    __syncthreads();

    // --- scale = sigmoid(h @ W2), W2 [16,256] row-major ---
    if (tid < NCH) {
        float sc = 0.f;
        #pragma unroll
        for (int j = 0; j < HID; ++j) sc += s_h[j] * W2[j * NCH + tid];
        s_vec[tid] = 1.0f / (1.0f + __expf(-sc));
    }
    __syncthreads();

    // --- pass 2: out = x * scale[g], 2 rows in flight, NT stores ---
    const f32x4 scv = *reinterpret_cast<const f32x4*>(&s_vec[c4 * 4]);
    r = start + rg;
    for (; r + 16 < end; r += 32) {
        f32x4 v0 = *reinterpret_cast<const f32x4*>(x + (size_t)(r     ) * NCH + coff);
        f32x4 v1 = *reinterpret_cast<const f32x4*>(x + (size_t)(r + 16) * NCH + coff);
        f32x4 o0 = v0 * scv;
        f32x4 o1 = v1 * scv;
        __builtin_nontemporal_store(o0, reinterpret_cast<f32x4*>(out + (size_t)(r     ) * NCH + coff));
        __builtin_nontemporal_store(o1, reinterpret_cast<f32x4*>(out + (size_t)(r + 16) * NCH + coff));
    }
    if (r < end) {
        f32x4 v0 = *reinterpret_cast<const f32x4*>(x + (size_t)r * NCH + coff);
        f32x4 o0 = v0 * scv;
        __builtin_nontemporal_store(o0, reinterpret_cast<f32x4*>(out + (size_t)r * NCH + coff));
    }
}

extern "C" void kernel_launch(void* const* d_in, const int* in_sizes, int n_in,
                              void* d_out, int out_size, void* d_ws, size_t ws_size,
                              hipStream_t stream) {
    const float* x     = (const float*)d_in[0];
    const int*   batch = (const int*)d_in[1];
    const float* W1    = (const float*)d_in[2];
    const float* W2    = (const float*)d_in[3];
    float*       out   = (float*)d_out;
    const int n = in_sizes[1];

    hipLaunchKernelGGL(graph_se_kernel, dim3(NGRAPH), dim3(1024), 0, stream,
                       x, batch, W1, W2, out, n);
}

// Round 4
// 266.550 us; speedup vs baseline: 1.1938x; 1.1023x over previous
//
#include <hip/hip_runtime.h>

#define NCH 256
#define HID 16
#define NBLK 256   // each block handles graphs b and b+256

typedef __attribute__((ext_vector_type(4))) float f32x4;

__device__ __forceinline__ f32x4 ldrow(const float* __restrict__ x, int r, size_t coff) {
    return *reinterpret_cast<const f32x4*>(x + (size_t)r * NCH + coff);
}

__device__ __forceinline__ void se_mlp(const float* __restrict__ W1,
                                       const float* __restrict__ W2,
                                       float (&s_part)[16][NCH],
                                       int first, int npart, int cnt,
                                       float* __restrict__ s_vec,
                                       float (&s_hp)[HID][17], float (&s_h)[HID],
                                       int tid)
{
    // mean
    if (tid < NCH) {
        float m = 0.f;
        for (int i = 0; i < npart; ++i) m += s_part[first + i][tid];
        m *= (cnt > 0) ? (1.0f / (float)cnt) : 1.0f;
        s_vec[tid] = m;                     // holds mean temporarily
    }
    __syncthreads();
    // h partials: 16 outputs x 16 sub-partials
    if (tid < NCH) {
        const int j = tid >> 4, sub = tid & 15;
        float hp = 0.f;
        #pragma unroll
        for (int i = 0; i < 16; ++i) { int c = sub * 16 + i; hp += s_vec[c] * W1[c * HID + j]; }
        s_hp[j][sub] = hp;
    }
    __syncthreads();
    if (tid < HID) {
        float h = 0.f;
        #pragma unroll
        for (int i = 0; i < 16; ++i) h += s_hp[tid][i];
        s_h[tid] = fmaxf(h, 0.f);
    }
    __syncthreads();
    // scale = sigmoid(h @ W2)
    if (tid < NCH) {
        float sc = 0.f;
        #pragma unroll
        for (int j = 0; j < HID; ++j) sc += s_h[j] * W2[j * NCH + tid];
        s_vec[tid] = 1.0f / (1.0f + __expf(-sc));
    }
}

__global__ __launch_bounds__(1024, 4) void graph_se_kernel(
    const float* __restrict__ x,
    const int* __restrict__ batch,
    const float* __restrict__ W1,
    const float* __restrict__ W2,
    float* __restrict__ out,
    int n)
{
    const int b   = blockIdx.x;
    const int tid = threadIdx.x;

    __shared__ int   s_bnd[4];
    __shared__ float s_part[16][NCH];
    __shared__ float s_vecA[NCH];
    __shared__ float s_vecB[NCH];
    __shared__ float s_hp[HID][17];
    __shared__ float s_h[HID];

    // boundaries of graphs b, b+1, b+256, b+257 (batch sorted)
    if (tid < 4) {
        int v = (tid < 2) ? (b + tid) : (NBLK + b + (tid - 2));
        int lo = 0, hi = n;
        while (lo < hi) { int mid = (lo + hi) >> 1; if (batch[mid] < v) lo = mid + 1; else hi = mid; }
        s_bnd[tid] = lo;
    }
    __syncthreads();
    const int loA = s_bnd[0], hiA = s_bnd[1];
    const int loB = s_bnd[2], hiB = s_bnd[3];

    const int rg = tid >> 6;            // row group 0..15 (wave id)
    const int c4 = tid & 63;            // float4 lane within row
    const size_t coff = (size_t)c4 * 4;

    // ---- P1: pool A, 16 groups, 8 loads in flight ----
    {
        f32x4 acc = (f32x4)(0.f);
        int r = loA + rg;
        for (; r + 112 < hiA; r += 128) {
            f32x4 v0 = ldrow(x, r      , coff);
            f32x4 v1 = ldrow(x, r +  16, coff);
            f32x4 v2 = ldrow(x, r +  32, coff);
            f32x4 v3 = ldrow(x, r +  48, coff);
            f32x4 v4 = ldrow(x, r +  64, coff);
            f32x4 v5 = ldrow(x, r +  80, coff);
            f32x4 v6 = ldrow(x, r +  96, coff);
            f32x4 v7 = ldrow(x, r + 112, coff);
            acc += ((v0 + v1) + (v2 + v3)) + ((v4 + v5) + (v6 + v7));
        }
        for (; r < hiA; r += 16) acc += ldrow(x, r, coff);
        *reinterpret_cast<f32x4*>(&s_part[rg][c4 * 4]) = acc;
    }
    __syncthreads();

    // ---- MLP A -> s_vecA ----
    se_mlp(W1, W2, s_part, 0, 16, hiA - loA, s_vecA, s_hp, s_h, tid);
    __syncthreads();

    // ---- P3: waves 0-7 scale+write A  ||  waves 8-15 pool B ----
    if (rg < 8) {
        const f32x4 scv = *reinterpret_cast<const f32x4*>(&s_vecA[c4 * 4]);
        int r = loA + rg;
        for (; r + 24 < hiA; r += 32) {
            f32x4 v0 = ldrow(x, r     , coff);
            f32x4 v1 = ldrow(x, r +  8, coff);
            f32x4 v2 = ldrow(x, r + 16, coff);
            f32x4 v3 = ldrow(x, r + 24, coff);
            f32x4 o0 = v0 * scv, o1 = v1 * scv, o2 = v2 * scv, o3 = v3 * scv;
            __builtin_nontemporal_store(o0, reinterpret_cast<f32x4*>(out + (size_t)(r     ) * NCH + coff));
            __builtin_nontemporal_store(o1, reinterpret_cast<f32x4*>(out + (size_t)(r +  8) * NCH + coff));
            __builtin_nontemporal_store(o2, reinterpret_cast<f32x4*>(out + (size_t)(r + 16) * NCH + coff));
            __builtin_nontemporal_store(o3, reinterpret_cast<f32x4*>(out + (size_t)(r + 24) * NCH + coff));
        }
        for (; r < hiA; r += 8) {
            f32x4 v0 = ldrow(x, r, coff);
            f32x4 o0 = v0 * scv;
            __builtin_nontemporal_store(o0, reinterpret_cast<f32x4*>(out + (size_t)r * NCH + coff));
        }
    } else {
        const int gid = rg - 8;
        f32x4 acc = (f32x4)(0.f);
        int r = loB + gid;
        for (; r + 56 < hiB; r += 64) {
            f32x4 v0 = ldrow(x, r     , coff);
            f32x4 v1 = ldrow(x, r +  8, coff);
            f32x4 v2 = ldrow(x, r + 16, coff);
            f32x4 v3 = ldrow(x, r + 24, coff);
            f32x4 v4 = ldrow(x, r + 32, coff);
            f32x4 v5 = ldrow(x, r + 40, coff);
            f32x4 v6 = ldrow(x, r + 48, coff);
            f32x4 v7 = ldrow(x, r + 56, coff);
            acc += ((v0 + v1) + (v2 + v3)) + ((v4 + v5) + (v6 + v7));
        }
        for (; r < hiB; r += 8) acc += ldrow(x, r, coff);
        *reinterpret_cast<f32x4*>(&s_part[rg][c4 * 4]) = acc;
    }
    __syncthreads();

    // ---- MLP B (partials 8..15) -> s_vecB ----
    se_mlp(W1, W2, s_part, 8, 8, hiB - loB, s_vecB, s_hp, s_h, tid);
    __syncthreads();

    // ---- P5: scale+write B, 16 groups ----
    {
        const f32x4 scv = *reinterpret_cast<const f32x4*>(&s_vecB[c4 * 4]);
        int r = loB + rg;
        for (; r + 48 < hiB; r += 64) {
            f32x4 v0 = ldrow(x, r     , coff);
            f32x4 v1 = ldrow(x, r + 16, coff);
            f32x4 v2 = ldrow(x, r + 32, coff);
            f32x4 v3 = ldrow(x, r + 48, coff);
            f32x4 o0 = v0 * scv, o1 = v1 * scv, o2 = v2 * scv, o3 = v3 * scv;
            __builtin_nontemporal_store(o0, reinterpret_cast<f32x4*>(out + (size_t)(r     ) * NCH + coff));
            __builtin_nontemporal_store(o1, reinterpret_cast<f32x4*>(out + (size_t)(r + 16) * NCH + coff));
            __builtin_nontemporal_store(o2, reinterpret_cast<f32x4*>(out + (size_t)(r + 32) * NCH + coff));
            __builtin_nontemporal_store(o3, reinterpret_cast<f32x4*>(out + (size_t)(r + 48) * NCH + coff));
        }
        for (; r < hiB; r += 16) {
            f32x4 v0 = ldrow(x, r, coff);
            f32x4 o0 = v0 * scv;
            __builtin_nontemporal_store(o0, reinterpret_cast<f32x4*>(out + (size_t)r * NCH + coff));
        }
    }
}

extern "C" void kernel_launch(void* const* d_in, const int* in_sizes, int n_in,
                              void* d_out, int out_size, void* d_ws, size_t ws_size,
                              hipStream_t stream) {
    const float* x     = (const float*)d_in[0];
    const int*   batch = (const int*)d_in[1];
    const float* W1    = (const float*)d_in[2];
    const float* W2    = (const float*)d_in[3];
    float*       out   = (float*)d_out;
    const int n = in_sizes[1];

    hipLaunchKernelGGL(graph_se_kernel, dim3(NBLK), dim3(1024), 0, stream,
                       x, batch, W1, W2, out, n);
}